// Round 3
// baseline (215.598 us; speedup 1.0000x reference)
//
#include <hip/hip_runtime.h>

// DCT compression: (32,3,512,512) fp32 -> (32,192,64,64) fp32
// Per 8x8 block: coef[a,u] = sum_{y,x} blk[y,x]*C8[a,y]*C8[u,x]
//   C8[u,y] = cos((u+0.5)*PI*y/8), PI = 3.1415 (module's approximation!)
// norm[a,u] = (a==0||u==0) ? sqrt(2)/8 : 0.25
// out[b, c*64 + z[a*8+u], hb, wb] = coef[a,u]*norm[a,u] / Qtab[c][z[a*8+u]]
//
// R3: writes were the wall (1.44 TB/s eff.: 256B chunks @ 16KB stride = DRAM
// channel camping). Fix: LDS transpose -> each store instr writes 1KB
// contiguous (lane-float4). Tables now constexpr (no init kernel). XCD
// swizzle so all 16 WGs of a bc share one XCD's L2.

#define PI_F 3.1415f

struct Tables {
    int   z[64];        // zigzag channel for coef index j=a*8+u
    float scl[2][64];   // norm(a,u)/Qtab[{luma,chroma}][z[j]]
};

constexpr Tables make_tables() {
    Tables t{};
    int p[64] = {};
    // faithful port of reference _zigzag(8) (verified on HW in R1/R2)
    for (int y = 0; y < 8; ++y)
        for (int x = (y & 1); x < 8 - y; x += 2) {
            int v = x + y + 1;
            p[y * 8 + x] = v * (v + 1) / 2 - x - 1;
        }
    for (int y = 0; y < 8; ++y)
        for (int x = ((y + 1) & 1); x < 8 - y; x += 2) {
            int v = x + y + 1;
            p[y * 8 + x] = v * (v + 1) / 2 - y - 1;
        }
    for (int y = 7; y >= 0; --y)
        for (int x = 7; x >= 8 - y; --x)
            p[y * 8 + x] = 63 - p[(7 - y) * 8 + (7 - x)];
    // Q=50 -> Q_luma = T exactly
    const int QT[2][64] = {
        {16,11,10,16,24,40,51,61, 12,12,14,19,26,58,60,55,
         14,13,16,24,40,57,69,56, 14,17,22,29,51,87,80,62,
         18,22,37,56,68,109,103,77, 24,35,55,64,81,104,113,92,
         49,64,78,87,103,121,120,101, 72,92,95,98,112,100,103,99},
        {17,18,24,47,99,99,99,99, 18,21,26,66,99,99,99,99,
         24,26,56,99,99,99,99,99, 47,66,99,99,99,99,99,99,
         99,99,99,99,99,99,99,99, 99,99,99,99,99,99,99,99,
         99,99,99,99,99,99,99,99, 99,99,99,99,99,99,99,99}
    };
    for (int i = 0; i < 64; ++i) {
        int a = i >> 3, u = i & 7;
        int zi = p[u * 8 + a];          // z = p.T
        t.z[i] = zi;
        float nrm = (a == 0 || u == 0) ? 0.17677669529663687f : 0.25f;
        t.scl[0][i] = nrm / (float)QT[0][zi];
        t.scl[1][i] = nrm / (float)QT[1][zi];
    }
    return t;
}
constexpr Tables TBL = make_tables();

// Grid: 1536 WGs x 256 threads. XCD swizzle: xcd = blockIdx&7 (RR dispatch),
//   k = blockIdx>>3; bc = xcd*12 + (k>>4) in [0,96); hbg = k&15.
//   wave = hb within group of 4; lane = wb. One lane = one 8x8 block.
__global__ __launch_bounds__(256, 4)
void DCTCompression_25786983645730_kernel(const float* __restrict__ x,
                                          float* __restrict__ out) {
    __shared__ float sC8[64];       // C8[u*8+y]
    __shared__ float st[32][256];   // transpose staging: 32 z-rows x 256 block-pos

    const int tid = threadIdx.x;
    const int k   = blockIdx.x >> 3;
    const int bc  = (blockIdx.x & 7) * 12 + (k >> 4);  // b*3+c
    const int hbg = k & 15;
    const int lc  = ((bc % 3) != 0);                   // 0=luma, 1=chroma

    if (tid < 64) {
        int u = tid >> 3, y = tid & 7;
        sC8[tid] = cosf(((float)u + 0.5f) * PI_F * ((float)y * 0.125f));
    }
    __syncthreads();

    const int wave = tid >> 6;
    const int lane = tid & 63;
    const int hb   = hbg * 4 + wave;

    // ---- load 8x8 block: 16 float4 loads, wave covers 16KB contiguous ----
    const float* xb = x + ((size_t)bc * 512 + (size_t)hb * 8) * 512 + lane * 8;
    float4 r[8][2];
#pragma unroll
    for (int y = 0; y < 8; ++y) {
        r[y][0] = *reinterpret_cast<const float4*>(xb + y * 512);
        r[y][1] = *reinterpret_cast<const float4*>(xb + y * 512 + 4);
    }

    // ---- 2D DCT into registers, scale folded in (compile-time literals) ----
    float c64[64];
#pragma unroll
    for (int a = 0; a < 8; ++a) {
        float tmp[8] = {0, 0, 0, 0, 0, 0, 0, 0};
#pragma unroll
        for (int y = 0; y < 8; ++y) {
            float cv = sC8[a * 8 + y];  // LDS broadcast
            tmp[0] = fmaf(cv, r[y][0].x, tmp[0]);
            tmp[1] = fmaf(cv, r[y][0].y, tmp[1]);
            tmp[2] = fmaf(cv, r[y][0].z, tmp[2]);
            tmp[3] = fmaf(cv, r[y][0].w, tmp[3]);
            tmp[4] = fmaf(cv, r[y][1].x, tmp[4]);
            tmp[5] = fmaf(cv, r[y][1].y, tmp[5]);
            tmp[6] = fmaf(cv, r[y][1].z, tmp[6]);
            tmp[7] = fmaf(cv, r[y][1].w, tmp[7]);
        }
#pragma unroll
        for (int u = 0; u < 8; ++u) {
            float acc = tmp[0] * sC8[u * 8 + 0];
#pragma unroll
            for (int xx = 1; xx < 8; ++xx)
                acc = fmaf(tmp[xx], sC8[u * 8 + xx], acc);
            const int j = a * 8 + u;
            const float s0 = TBL.scl[0][j], s1 = TBL.scl[1][j];  // literals
            c64[j] = acc * (lc ? s1 : s0);
        }
    }

    // out base: element = bc*64*4096 + z*4096 + hbg*256 + t, t = lane*4 in write phase
    float* ob = out + (size_t)bc * 262144 + (size_t)hbg * 256 + lane * 4;

    // ---- two transpose passes: stage z in [pass*32, pass*32+32) ----
#pragma unroll
    for (int pass = 0; pass < 2; ++pass) {
#pragma unroll
        for (int j = 0; j < 64; ++j) {
            const int zi = TBL.z[j];            // compile-time
            if ((zi >> 5) == pass)
                st[zi & 31][(wave << 6) | lane] = c64[j];  // banks=lane%32, 2-way: free
        }
        __syncthreads();
        // each wave writes 8 channel-chunks of 1KB contiguous
#pragma unroll
        for (int i = 0; i < 8; ++i) {
            const int zl = i * 4 + wave;        // waves cover 4 consecutive z
            float4 v = *reinterpret_cast<const float4*>(&st[zl][lane * 4]);
            *reinterpret_cast<float4*>(ob + (size_t)(pass * 32 + zl) * 4096) = v;
        }
        __syncthreads();  // protect st before next pass re-stages
    }
}

extern "C" void kernel_launch(void* const* d_in, const int* in_sizes, int n_in,
                              void* d_out, int out_size, void* d_ws, size_t ws_size,
                              hipStream_t stream) {
    const float* x = (const float*)d_in[0];
    float* out = (float*)d_out;
    // 8 XCDs * 12 bc * 16 hbg = 1536 workgroups
    DCTCompression_25786983645730_kernel<<<dim3(1536), dim3(256), 0, stream>>>(x, out);
}

// Round 4
// 190.476 us; speedup vs baseline: 1.1319x; 1.1319x over previous
//
#include <hip/hip_runtime.h>

// DCT compression: (32,3,512,512) fp32 -> (32,192,64,64) fp32
// Per 8x8 block: coef[a,u] = sum_{y,x} blk[y,x]*C8[a,y]*C8[u,x]
//   C8[u,y] = cos((u+0.5)*PI*y/8), PI = 3.1415 (module's approximation!)
// norm[a,u] = (a==0||u==0) ? sqrt(2)/8 : 0.25
// out[b, c*64 + z[a*8+u], hb, wb] = coef[a,u]*norm[a,u] / Qtab[c][z[a*8+u]]
//
// R4: R3's LDS-transpose (1KB contiguous stores) WITHOUT the register spill:
//  - full 64x256 staging buffer (64KB LDS), coefs scattered to LDS as computed
//    (no c64[64] live array -> ~90 VGPR, launch_bounds(256,2) caps at 256)
//  - single __syncthreads, then 64 x 1KB dwordx4 streaming stores
// R3 lesson: VGPR_Count=64 + WRITE 176MB = compiler spilled c64 to scratch.

#define PI_F 3.1415f

struct Tables {
    int   z[64];        // zigzag channel for coef index j=a*8+u
    float scl[2][64];   // norm(a,u)/Qtab[{luma,chroma}][z[j]]
};

constexpr Tables make_tables() {
    Tables t{};
    int p[64] = {};
    // faithful port of reference _zigzag(8) (HW-verified R1-R3)
    for (int y = 0; y < 8; ++y)
        for (int x = (y & 1); x < 8 - y; x += 2) {
            int v = x + y + 1;
            p[y * 8 + x] = v * (v + 1) / 2 - x - 1;
        }
    for (int y = 0; y < 8; ++y)
        for (int x = ((y + 1) & 1); x < 8 - y; x += 2) {
            int v = x + y + 1;
            p[y * 8 + x] = v * (v + 1) / 2 - y - 1;
        }
    for (int y = 7; y >= 0; --y)
        for (int x = 7; x >= 8 - y; --x)
            p[y * 8 + x] = 63 - p[(7 - y) * 8 + (7 - x)];
    const int QT[2][64] = {
        {16,11,10,16,24,40,51,61, 12,12,14,19,26,58,60,55,
         14,13,16,24,40,57,69,56, 14,17,22,29,51,87,80,62,
         18,22,37,56,68,109,103,77, 24,35,55,64,81,104,113,92,
         49,64,78,87,103,121,120,101, 72,92,95,98,112,100,103,99},
        {17,18,24,47,99,99,99,99, 18,21,26,66,99,99,99,99,
         24,26,56,99,99,99,99,99, 47,66,99,99,99,99,99,99,
         99,99,99,99,99,99,99,99, 99,99,99,99,99,99,99,99,
         99,99,99,99,99,99,99,99, 99,99,99,99,99,99,99,99}
    };
    for (int i = 0; i < 64; ++i) {
        int a = i >> 3, u = i & 7;
        int zi = p[u * 8 + a];          // z = p.T
        t.z[i] = zi;
        float nrm = (a == 0 || u == 0) ? 0.17677669529663687f : 0.25f;
        t.scl[0][i] = nrm / (float)QT[0][zi];
        t.scl[1][i] = nrm / (float)QT[1][zi];
    }
    return t;
}
constexpr Tables TBL = make_tables();

// Grid: 1536 WGs x 256 threads. XCD swizzle: xcd = blockIdx&7 (RR dispatch),
//   k = blockIdx>>3; bc = (blockIdx&7)*12 + (k>>4); hbg = k&15.
//   wave covers hb = hbg*4+wave; lane = wb. One lane = one 8x8 block.
__global__ __launch_bounds__(256, 2)
void DCTCompression_25786983645730_kernel(const float* __restrict__ x,
                                          float* __restrict__ out) {
    __shared__ float sC8[64];      // C8[u*8+y]
    __shared__ float st[64][256];  // full transpose staging: z x block-pos (64KB)

    const int tid = threadIdx.x;
    const int k   = blockIdx.x >> 3;
    const int bc  = (blockIdx.x & 7) * 12 + (k >> 4);  // b*3+c
    const int hbg = k & 15;
    const int lc  = ((bc % 3) != 0);                   // 0=luma, 1=chroma

    if (tid < 64) {
        int u = tid >> 3, y = tid & 7;
        sC8[tid] = cosf(((float)u + 0.5f) * PI_F * ((float)y * 0.125f));
    }
    __syncthreads();

    const int wave = tid >> 6;
    const int lane = tid & 63;
    const int hb   = hbg * 4 + wave;
    const int pos  = (wave << 6) | lane;  // block index within WG [0,256)

    // ---- load 8x8 block: 16 float4 loads, wave covers 16KB contiguous ----
    const float* xb = x + ((size_t)bc * 512 + (size_t)hb * 8) * 512 + lane * 8;
    float4 r[8][2];
#pragma unroll
    for (int y = 0; y < 8; ++y) {
        r[y][0] = *reinterpret_cast<const float4*>(xb + y * 512);
        r[y][1] = *reinterpret_cast<const float4*>(xb + y * 512 + 4);
    }

    // ---- 2D DCT; each coef scattered to LDS immediately (no c64 array) ----
#pragma unroll
    for (int a = 0; a < 8; ++a) {
        float tmp[8] = {0, 0, 0, 0, 0, 0, 0, 0};
#pragma unroll
        for (int y = 0; y < 8; ++y) {
            float cv = sC8[a * 8 + y];  // LDS broadcast
            tmp[0] = fmaf(cv, r[y][0].x, tmp[0]);
            tmp[1] = fmaf(cv, r[y][0].y, tmp[1]);
            tmp[2] = fmaf(cv, r[y][0].z, tmp[2]);
            tmp[3] = fmaf(cv, r[y][0].w, tmp[3]);
            tmp[4] = fmaf(cv, r[y][1].x, tmp[4]);
            tmp[5] = fmaf(cv, r[y][1].y, tmp[5]);
            tmp[6] = fmaf(cv, r[y][1].z, tmp[6]);
            tmp[7] = fmaf(cv, r[y][1].w, tmp[7]);
        }
#pragma unroll
        for (int u = 0; u < 8; ++u) {
            float acc = tmp[0] * sC8[u * 8 + 0];
#pragma unroll
            for (int xx = 1; xx < 8; ++xx)
                acc = fmaf(tmp[xx], sC8[u * 8 + xx], acc);
            const int j = a * 8 + u;
            const float s = lc ? TBL.scl[1][j] : TBL.scl[0][j];  // literals
            st[TBL.z[j]][pos] = acc * s;  // ds_write, const z -> imm offset
        }
    }
    __syncthreads();

    // ---- stream out: 64 chunks of 1KB contiguous (lane-float4) ----
    float* ob = out + (size_t)bc * 262144 + (size_t)hbg * 256 + lane * 4;
#pragma unroll
    for (int i = 0; i < 16; ++i) {
        const int zl = i * 4 + wave;
        float4 v = *reinterpret_cast<const float4*>(&st[zl][lane * 4]);
        __builtin_nontemporal_store(v.x, ob + (size_t)zl * 4096 + 0);
        __builtin_nontemporal_store(v.y, ob + (size_t)zl * 4096 + 1);
        __builtin_nontemporal_store(v.z, ob + (size_t)zl * 4096 + 2);
        __builtin_nontemporal_store(v.w, ob + (size_t)zl * 4096 + 3);
    }
}

extern "C" void kernel_launch(void* const* d_in, const int* in_sizes, int n_in,
                              void* d_out, int out_size, void* d_ws, size_t ws_size,
                              hipStream_t stream) {
    const float* x = (const float*)d_in[0];
    float* out = (float*)d_out;
    // 8 XCDs * 12 bc * 16 hbg = 1536 workgroups
    DCTCompression_25786983645730_kernel<<<dim3(1536), dim3(256), 0, stream>>>(x, out);
}